// Round 1
// baseline (277.094 us; speedup 1.0000x reference)
//
#include <hip/hip_runtime.h>
#include <hip/hip_bf16.h>

// Problem constants
#define Bc 2
#define Nc 6
#define Cc 64
#define Hc 28
#define Wc 50
#define Dc 59
#define BHc 200
#define BWc 200
// BEV_X0 = BEV_Y0 = -50.0, RES = 0.5

// One wave (64 lanes) per pixel (b,n,h,w). lane = channel c.
// Geometry computed per-wave in f32 with exact reference association
// (no FMA contraction) to reproduce truncation-boundary bins bit-exactly.
__global__ __launch_bounds__(256) void fp_scatter_kernel(
    const float* __restrict__ feats,   // (B,N,C,H,W)
    const float* __restrict__ depth,   // (B,N,D,H,W)
    const float* __restrict__ Kmat,    // (B,N,3,3)
    const float* __restrict__ Emat,    // (B,N,4,4)
    float* __restrict__ acc,
    int direct)                        // 0: acc=(B,BH,BW,C)  1: acc=(B,C,BH,BW)
{
    const int NPIX = Bc * Nc * Hc * Wc;            // 16800
    int wave = (blockIdx.x * blockDim.x + threadIdx.x) >> 6;
    int lane = threadIdx.x & 63;
    if (wave >= NPIX) return;

    int w = wave % Wc;
    int h = (wave / Wc) % Hc;
    int n = (wave / (Wc * Hc)) % Nc;
    int b = wave / (Wc * Hc * Nc);

    // ---- K inverse (f32 adjugate, correctly-rounded division) ----
    const float* K = Kmat + (size_t)(b * Nc + n) * 9;
    float k00 = K[0], k01 = K[1], k02 = K[2];
    float k10 = K[3], k11 = K[4], k12 = K[5];
    float k20 = K[6], k21 = K[7], k22 = K[8];

    float c00 = __fsub_rn(__fmul_rn(k11, k22), __fmul_rn(k12, k21));
    float c01 = __fsub_rn(__fmul_rn(k12, k20), __fmul_rn(k10, k22));
    float c02 = __fsub_rn(__fmul_rn(k10, k21), __fmul_rn(k11, k20));
    float det = __fadd_rn(__fadd_rn(__fmul_rn(k00, c00), __fmul_rn(k01, c01)),
                          __fmul_rn(k02, c02));
    // inv[i][j] = cof(j,i)/det
    float i00 = __fdiv_rn(c00, det);
    float i01 = __fdiv_rn(__fsub_rn(__fmul_rn(k02, k21), __fmul_rn(k01, k22)), det);
    float i02 = __fdiv_rn(__fsub_rn(__fmul_rn(k01, k12), __fmul_rn(k02, k11)), det);
    float i10 = __fdiv_rn(c01, det);
    float i11 = __fdiv_rn(__fsub_rn(__fmul_rn(k00, k22), __fmul_rn(k02, k20)), det);
    float i12 = __fdiv_rn(__fsub_rn(__fmul_rn(k02, k10), __fmul_rn(k00, k12)), det);
    float i20 = __fdiv_rn(c02, det);
    float i21 = __fdiv_rn(__fsub_rn(__fmul_rn(k01, k20), __fmul_rn(k00, k21)), det);
    float i22 = __fdiv_rn(__fsub_rn(__fmul_rn(k00, k11), __fmul_rn(k01, k10)), det);

    // ---- R, t from extrinsics ----
    const float* E = Emat + (size_t)(b * Nc + n) * 16;
    float r00 = E[0], r01 = E[1], r02 = E[2],  tx = E[3];
    float r10 = E[4], r11 = E[5], r12 = E[6],  ty = E[7];
    float r20 = E[8], r21 = E[9], r22 = E[10], tz = E[11];

    // ---- per-lane feature value ----
    const size_t HW = (size_t)Hc * Wc;
    float feat = feats[((size_t)(b * Nc + n) * Cc + lane) * HW + (size_t)h * Wc + w];
    const float* dptr = depth + (size_t)(b * Nc + n) * Dc * HW + (size_t)h * Wc + w;

    float xf = (float)w;
    float yf = (float)h;

    for (int d = 0; d < Dc; ++d) {
        float db = (float)(d + 1);                       // depth bins 1..59
        float px = __fmul_rn(xf, db);
        float py = __fmul_rn(yf, db);
        float pz = db;

        // cam = Kinv @ (px,py,pz): ((m0*v0 + m1*v1) + m2*v2)
        float cx = __fadd_rn(__fadd_rn(__fmul_rn(i00, px), __fmul_rn(i01, py)), __fmul_rn(i02, pz));
        float cy = __fadd_rn(__fadd_rn(__fmul_rn(i10, px), __fmul_rn(i11, py)), __fmul_rn(i12, pz));
        float cz = __fadd_rn(__fadd_rn(__fmul_rn(i20, px), __fmul_rn(i21, py)), __fmul_rn(i22, pz));

        // ego = R @ cam + t (add t after the 3-term sum, like the reference)
        float ex = __fadd_rn(__fadd_rn(__fadd_rn(__fmul_rn(r00, cx), __fmul_rn(r01, cy)), __fmul_rn(r02, cz)), tx);
        float ey = __fadd_rn(__fadd_rn(__fadd_rn(__fmul_rn(r10, cx), __fmul_rn(r11, cy)), __fmul_rn(r12, cz)), ty);
        float ez = __fadd_rn(__fadd_rn(__fadd_rn(__fmul_rn(r20, cx), __fmul_rn(r21, cy)), __fmul_rn(r22, cz)), tz);

        // bx = int((x - (-50)) / 0.5), truncation toward zero
        int bx = (int)(__fmul_rn(__fadd_rn(ex, 50.0f), 2.0f));
        int by = (int)(__fmul_rn(__fadd_rn(ey, 50.0f), 2.0f));

        bool valid = (bx >= 0) & (bx < BWc) & (by >= 0) & (by < BHc) & (ez > 0.0f);
        if (valid) {
            float dep = dptr[(size_t)d * HW];
            size_t idx;
            if (direct)
                idx = (((size_t)(b * Cc + lane) * BHc + by) * BWc + bx);
            else
                idx = (((size_t)(b * BHc + by) * BWc + bx) * Cc + lane);
            atomicAdd(&acc[idx], __fmul_rn(feat, dep));
        }
    }
}

// (B, BH*BW, C) -> (B, C, BH*BW), LDS-tiled 64x64
__global__ __launch_bounds__(256) void fp_transpose_kernel(
    const float* __restrict__ acc, float* __restrict__ out)
{
    __shared__ float tile[64][65];
    const int P = BHc * BWc;                 // 40000, divisible by 64
    int b = blockIdx.y;
    int p0 = blockIdx.x * 64;
    int tx = threadIdx.x & 63;
    int ty = threadIdx.x >> 6;               // 0..3

    const float* src = acc + (size_t)b * P * Cc;
#pragma unroll
    for (int i = 0; i < 16; ++i) {
        int row = ty * 16 + i;
        tile[row][tx] = src[(size_t)(p0 + row) * Cc + tx];
    }
    __syncthreads();
    float* dst = out + (size_t)b * Cc * P;
#pragma unroll
    for (int i = 0; i < 16; ++i) {
        int c = ty * 16 + i;
        dst[(size_t)c * P + p0 + tx] = tile[tx][c];
    }
}

extern "C" void kernel_launch(void* const* d_in, const int* in_sizes, int n_in,
                              void* d_out, int out_size, void* d_ws, size_t ws_size,
                              hipStream_t stream) {
    const float* feats = (const float*)d_in[0];
    const float* depth = (const float*)d_in[1];
    const float* Kmat  = (const float*)d_in[2];
    const float* Emat  = (const float*)d_in[3];
    float* out = (float*)d_out;

    const size_t ACC_ELEMS = (size_t)Bc * BHc * BWc * Cc;   // 5,120,000
    const size_t ACC_BYTES = ACC_ELEMS * sizeof(float);     // 20.48 MB

    bool use_ws = (ws_size >= ACC_BYTES);
    float* acc = use_ws ? (float*)d_ws : out;

    hipMemsetAsync(acc, 0, ACC_BYTES, stream);

    const int NPIX = Bc * Nc * Hc * Wc;      // 16800
    int blocks = (NPIX + 3) / 4;             // 4 waves per 256-thread block
    fp_scatter_kernel<<<blocks, 256, 0, stream>>>(feats, depth, Kmat, Emat,
                                                  acc, use_ws ? 0 : 1);
    if (use_ws) {
        fp_transpose_kernel<<<dim3((BHc * BWc) / 64, Bc), 256, 0, stream>>>(acc, out);
    }
}

// Round 2
// 110.242 us; speedup vs baseline: 2.5135x; 2.5135x over previous
//
#include <hip/hip_runtime.h>
#include <hip/hip_bf16.h>

// Problem constants
#define Bc 2
#define Nc 6
#define Cc 64
#define Hc 28
#define Wc 50
#define Dc 59
#define BHc 200
#define BWc 200
// BEV_X0 = BEV_Y0 = -50.0, RES = 0.5

// One block per (b,n,w). lane = channel c. Waves split the D bins.
// For each d: lanes 0..27 compute the exact reference f32 chain for h=lane,
// ballot validity, pre-sum all h sharing the first valid bin, issue ONE
// 64-lane atomic. Fallback handles h with differing bins (general case).
__global__ __launch_bounds__(256) void fp_scatter2(
    const float* __restrict__ feats,   // (B,N,C,H,W)
    const float* __restrict__ depth,   // (B,N,D,H,W)
    const float* __restrict__ Kmat,    // (B,N,3,3)
    const float* __restrict__ Emat,    // (B,N,4,4)
    float* __restrict__ acc)           // (B, BH*BW, C)
{
    __shared__ float feat_lds[Hc][Cc];   // [h][c]
    __shared__ float dep_lds[Dc][Hc];    // [d][h]

    int blk = blockIdx.x;                // (b*N + n)*W + w
    int w  = blk % Wc;
    int bn = blk / Wc;
    int b  = bn / Nc;
    int tid  = threadIdx.x;
    int lane = tid & 63;
    int wid  = tid >> 6;

    const size_t HW = (size_t)Hc * Wc;
    const float* fbase = feats + (size_t)bn * Cc * HW + w;
    const float* dbase = depth + (size_t)bn * Dc * HW + w;

    // Stage feat column: feat_lds[h][c] = feats[b,n,c,h,w]
    for (int h = wid; h < Hc; h += 4)
        feat_lds[h][lane] = fbase[(size_t)lane * HW + (size_t)h * Wc];
    // Stage depth column: dep_lds[d][h] = depth[b,n,d,h,w]
    for (int idx = tid; idx < Dc * Hc; idx += 256) {
        int d = idx / Hc, h = idx % Hc;
        dep_lds[d][h] = dbase[(size_t)d * HW + (size_t)h * Wc];
    }

    // ---- K inverse (f32 adjugate, correctly-rounded division) ----
    const float* K = Kmat + (size_t)bn * 9;
    float k00 = K[0], k01 = K[1], k02 = K[2];
    float k10 = K[3], k11 = K[4], k12 = K[5];
    float k20 = K[6], k21 = K[7], k22 = K[8];

    float c00 = __fsub_rn(__fmul_rn(k11, k22), __fmul_rn(k12, k21));
    float c01 = __fsub_rn(__fmul_rn(k12, k20), __fmul_rn(k10, k22));
    float c02 = __fsub_rn(__fmul_rn(k10, k21), __fmul_rn(k11, k20));
    float det = __fadd_rn(__fadd_rn(__fmul_rn(k00, c00), __fmul_rn(k01, c01)),
                          __fmul_rn(k02, c02));
    float i00 = __fdiv_rn(c00, det);
    float i01 = __fdiv_rn(__fsub_rn(__fmul_rn(k02, k21), __fmul_rn(k01, k22)), det);
    float i02 = __fdiv_rn(__fsub_rn(__fmul_rn(k01, k12), __fmul_rn(k02, k11)), det);
    float i10 = __fdiv_rn(c01, det);
    float i11 = __fdiv_rn(__fsub_rn(__fmul_rn(k00, k22), __fmul_rn(k02, k20)), det);
    float i12 = __fdiv_rn(__fsub_rn(__fmul_rn(k02, k10), __fmul_rn(k00, k12)), det);
    float i20 = __fdiv_rn(c02, det);
    float i21 = __fdiv_rn(__fsub_rn(__fmul_rn(k01, k20), __fmul_rn(k00, k21)), det);
    float i22 = __fdiv_rn(__fsub_rn(__fmul_rn(k00, k11), __fmul_rn(k01, k10)), det);

    const float* E = Emat + (size_t)bn * 16;
    float r00 = E[0], r01 = E[1], r02 = E[2],  tx = E[3];
    float r10 = E[4], r11 = E[5], r12 = E[6],  ty = E[7];
    float r20 = E[8], r21 = E[9], r22 = E[10], tz = E[11];

    __syncthreads();

    float xf = (float)w;
    float* accb = acc + (size_t)b * (BHc * BWc) * Cc;

    for (int d = wid; d < Dc; d += 4) {
        float db = (float)(d + 1);           // depth bins 1..59

        // ---- phase 1: lane h = lane computes exact reference chain ----
        int h = lane;
        float yf = (float)h;
        float px = __fmul_rn(xf, db);
        float py = __fmul_rn(yf, db);
        float pz = db;

        float cx = __fadd_rn(__fadd_rn(__fmul_rn(i00, px), __fmul_rn(i01, py)), __fmul_rn(i02, pz));
        float cy = __fadd_rn(__fadd_rn(__fmul_rn(i10, px), __fmul_rn(i11, py)), __fmul_rn(i12, pz));
        float cz = __fadd_rn(__fadd_rn(__fmul_rn(i20, px), __fmul_rn(i21, py)), __fmul_rn(i22, pz));

        float ex = __fadd_rn(__fadd_rn(__fadd_rn(__fmul_rn(r00, cx), __fmul_rn(r01, cy)), __fmul_rn(r02, cz)), tx);
        float ey = __fadd_rn(__fadd_rn(__fadd_rn(__fmul_rn(r10, cx), __fmul_rn(r11, cy)), __fmul_rn(r12, cz)), ty);
        float ez = __fadd_rn(__fadd_rn(__fadd_rn(__fmul_rn(r20, cx), __fmul_rn(r21, cy)), __fmul_rn(r22, cz)), tz);

        int bx = (int)(__fmul_rn(__fadd_rn(ex, 50.0f), 2.0f));
        int by = (int)(__fmul_rn(__fadd_rn(ey, 50.0f), 2.0f));

        bool valid = (h < Hc) & (bx >= 0) & (bx < BWc) & (by >= 0) & (by < BHc) & (ez > 0.0f);
        int binidx = by * BWc + bx;

        unsigned long long vm = __ballot(valid);
        if (vm == 0ULL) continue;            // wave-uniform

        int first = __builtin_ctzll(vm);
        int prim  = __shfl(binidx, first);
        unsigned long long match = __ballot(valid && (binidx == prim));
        unsigned long long rest  = vm & ~match;

        // ---- phase 2: all 64 lanes (lane = c) pre-sum matching h's ----
        float accv = 0.0f;
        for (unsigned long long m = match; m; m &= (m - 1)) {
            int hh = __builtin_ctzll(m);
            accv = __fmaf_rn(feat_lds[hh][lane], dep_lds[d][hh], accv);
        }
        atomicAdd(&accb[(size_t)prim * Cc + lane], accv);

        // ---- fallback: valid h with a different bin (general case) ----
        while (rest) {
            int hh = __builtin_ctzll(rest);
            rest &= rest - 1;
            int bidx = __shfl(binidx, hh);
            atomicAdd(&accb[(size_t)bidx * Cc + lane],
                      __fmul_rn(feat_lds[hh][lane], dep_lds[d][hh]));
        }
    }
}

// (B, BH*BW, C) -> (B, C, BH*BW), LDS-tiled 64x64
__global__ __launch_bounds__(256) void fp_transpose_kernel(
    const float* __restrict__ acc, float* __restrict__ out)
{
    __shared__ float tile[64][65];
    const int P = BHc * BWc;                 // 40000, divisible by 64
    int b = blockIdx.y;
    int p0 = blockIdx.x * 64;
    int tx = threadIdx.x & 63;
    int ty = threadIdx.x >> 6;               // 0..3

    const float* src = acc + (size_t)b * P * Cc;
#pragma unroll
    for (int i = 0; i < 16; ++i) {
        int row = ty * 16 + i;
        tile[row][tx] = src[(size_t)(p0 + row) * Cc + tx];
    }
    __syncthreads();
    float* dst = out + (size_t)b * Cc * P;
#pragma unroll
    for (int i = 0; i < 16; ++i) {
        int c = ty * 16 + i;
        dst[(size_t)c * P + p0 + tx] = tile[tx][c];
    }
}

extern "C" void kernel_launch(void* const* d_in, const int* in_sizes, int n_in,
                              void* d_out, int out_size, void* d_ws, size_t ws_size,
                              hipStream_t stream) {
    const float* feats = (const float*)d_in[0];
    const float* depth = (const float*)d_in[1];
    const float* Kmat  = (const float*)d_in[2];
    const float* Emat  = (const float*)d_in[3];
    float* out = (float*)d_out;

    const size_t ACC_ELEMS = (size_t)Bc * BHc * BWc * Cc;   // 5,120,000
    const size_t ACC_BYTES = ACC_ELEMS * sizeof(float);     // 20.48 MB
    float* acc = (float*)d_ws;   // ws is ample (>= out_size)

    hipMemsetAsync(acc, 0, ACC_BYTES, stream);

    const int NBLK = Bc * Nc * Wc;           // 600 blocks: one per (b,n,w)
    fp_scatter2<<<NBLK, 256, 0, stream>>>(feats, depth, Kmat, Emat, acc);

    fp_transpose_kernel<<<dim3((BHc * BWc) / 64, Bc), 256, 0, stream>>>(acc, out);
}